// Round 4
// baseline (443.171 us; speedup 1.0000x reference)
//
#include <hip/hip_runtime.h>
#include <math.h>
#include <stdint.h>

#define BATCH 8
#define CH    512
#define SEQ   2048
#define CKDIM 64

typedef __attribute__((ext_vector_type(8))) short bf16x8;
typedef __attribute__((ext_vector_type(4))) float f32x4;

__device__ __forceinline__ unsigned short f2b(float f) {
    union { float f; uint32_t u; } v; v.f = f;
    uint32_t u = v.u;
    u += 0x7fffu + ((u >> 16) & 1u);   // round-to-nearest-even
    return (unsigned short)(u >> 16);
}

// ---------------------------------------------------------------------------
// x (B, C, L) fp32  ->  xt (B, L, C) bf16   (64x64 LDS-tiled transpose+cast)
// ---------------------------------------------------------------------------
__global__ __launch_bounds__(256) void transpose_cast_kernel(
    const float* __restrict__ x, unsigned short* __restrict__ xt)
{
    __shared__ float t[64][65];
    const int b = blockIdx.z, l0 = blockIdx.x * 64, c0 = blockIdx.y * 64;
    const int tx = threadIdx.x & 63, ty = threadIdx.x >> 6;
    #pragma unroll
    for (int q = 0; q < 16; ++q)
        t[ty + q * 4][tx] = x[((size_t)b * CH + c0 + ty + q * 4) * SEQ + l0 + tx];
    __syncthreads();
    #pragma unroll
    for (int q = 0; q < 16; ++q)
        xt[((size_t)b * SEQ + l0 + ty + q * 4) * CH + c0 + tx] = f2b(t[tx][ty + q * 4]);
}

// ---------------------------------------------------------------------------
// Weight cast: Wfg_b = concat(Wf, Wg) bf16 (128 x 512), Wh_b bf16 (512 x 512),
// bias_fg fp32[128] = concat(bf, bg).
// ---------------------------------------------------------------------------
__global__ __launch_bounds__(256) void castw_kernel(
    const float* __restrict__ Wf, const float* __restrict__ Wg,
    const float* __restrict__ Wh, const float* __restrict__ bf_,
    const float* __restrict__ bg_, unsigned short* __restrict__ Wfgb,
    unsigned short* __restrict__ Whb, float* __restrict__ bias_fg)
{
    const int i = blockIdx.x * 256 + threadIdx.x;
    if (i < 128) bias_fg[i] = (i < 64) ? bf_[i] : bg_[i - 64];
    if (i < 65536) Wfgb[i] = f2b((i < 32768) ? Wf[i] : Wg[i - 32768]);
    if (i < 262144) Whb[i] = f2b(Wh[i]);
}

// ---------------------------------------------------------------------------
// NT bf16 GEMM core (proven round 3: 0 LDS bank conflicts).
// C(128x128) += A(128xK) * B(128xK)^T, rows K-contiguous.
// ---------------------------------------------------------------------------
__device__ __attribute__((always_inline)) inline void gemm_core_nt(
    const unsigned short* __restrict__ A, const int ldA,
    const unsigned short* __restrict__ B, const int ldB,
    const int K,
    unsigned short* __restrict__ ldsA, unsigned short* __restrict__ ldsB,
    f32x4 acc[4][4])
{
    const int tid  = threadIdx.x;
    const int lane = tid & 63;
    const int wm   = tid >> 7;
    const int wn   = (tid >> 6) & 1;
    const int fr   = lane & 15;
    const int hi   = lane >> 4;
    const int xo   = lane & 7;

    int goA[4], goB[4], lo[4];
    #pragma unroll
    for (int it = 0; it < 4; ++it) {
        const int idx = tid + it * 256;
        const int row = idx >> 3;
        const int ch  = idx & 7;
        goA[it] = row * ldA + ch * 8;
        goB[it] = row * ldB + ch * 8;
        lo[it]  = row * 64 + ((ch ^ (row & 7)) * 8);
    }
    int aoff[4], boff[4];
    #pragma unroll
    for (int f = 0; f < 4; ++f) {
        aoff[f] = (wm * 64 + f * 16 + fr) * 64;
        boff[f] = (wn * 64 + f * 16 + fr) * 64;
    }
    const int coff0 = ((0 + hi) ^ xo) * 8;
    const int coff1 = ((4 + hi) ^ xo) * 8;

    uint4 ra[4], rb[4];
    #pragma unroll
    for (int it = 0; it < 4; ++it) {
        ra[it] = *(const uint4*)(A + goA[it]);
        rb[it] = *(const uint4*)(B + goB[it]);
    }

    for (int k0 = 0; k0 < K; k0 += 64) {
        #pragma unroll
        for (int it = 0; it < 4; ++it) {
            *(uint4*)&ldsA[lo[it]] = ra[it];
            *(uint4*)&ldsB[lo[it]] = rb[it];
        }
        __syncthreads();
        if (k0 + 64 < K) {
            #pragma unroll
            for (int it = 0; it < 4; ++it) {
                ra[it] = *(const uint4*)(A + goA[it] + k0 + 64);
                rb[it] = *(const uint4*)(B + goB[it] + k0 + 64);
            }
        }
        #pragma unroll
        for (int kk = 0; kk < 2; ++kk) {
            const int co = kk ? coff1 : coff0;
            bf16x8 af[4], bg[4];
            #pragma unroll
            for (int f = 0; f < 4; ++f) {
                af[f] = *(const bf16x8*)&ldsA[aoff[f] + co];
                bg[f] = *(const bf16x8*)&ldsB[boff[f] + co];
            }
            #pragma unroll
            for (int m = 0; m < 4; ++m)
                #pragma unroll
                for (int n = 0; n < 4; ++n)
                    acc[m][n] = __builtin_amdgcn_mfma_f32_16x16x32_bf16(
                        af[m], bg[n], acc[m][n], 0, 0, 0);
        }
        __syncthreads();
    }
}

__device__ __attribute__((always_inline)) inline void epilogue_store_bf16(
    unsigned short* __restrict__ lds, f32x4 acc[4][4],
    unsigned short* __restrict__ outBase, const int ldOut,
    const float* __restrict__ rowBias, const float* __restrict__ colBias)
{
    const int tid = threadIdx.x;
    const int lane = tid & 63;
    const int wm = tid >> 7, wn = (tid >> 6) & 1;
    const int fr = lane & 15, hi = lane >> 4;
    #pragma unroll
    for (int m = 0; m < 4; ++m) {
        const int m0 = wm * 64 + m * 16 + hi * 4;
        #pragma unroll
        for (int n = 0; n < 4; ++n) {
            const int nn = wn * 64 + n * 16 + fr;
            const float cb = colBias ? colBias[nn] : 0.f;
            #pragma unroll
            for (int e = 0; e < 4; ++e) {
                float v = acc[m][n][e] + cb;
                if (rowBias) v += rowBias[m0 + e];
                lds[(m0 + e) * 128 + nn] = f2b(v);
            }
        }
    }
    __syncthreads();
    #pragma unroll
    for (int q = 0; q < 8; ++q) {
        const int idx = tid + q * 256;
        const int row = idx >> 4, ch = idx & 15;
        *(uint4*)&outBase[(size_t)row * ldOut + ch * 8] =
            *(const uint4*)&lds[row * 128 + ch * 8];
    }
}

// ---------------------------------------------------------------------------
// proj_fg: fg_t[b][i][n] = sum_c xt[b][i][c] * Wfg[n][c] + bias_fg[n]
// ---------------------------------------------------------------------------
__global__ __launch_bounds__(256) void proj_fg_kernel(
    const unsigned short* __restrict__ xt, const unsigned short* __restrict__ Wfg,
    const float* __restrict__ bias_fg, unsigned short* __restrict__ fg_t)
{
    __shared__ unsigned short lds[16384];
    const int b = blockIdx.z, i0 = blockIdx.x * 128;
    const unsigned short* A = xt + ((size_t)b * SEQ + i0) * CH;
    f32x4 acc[4][4];
    const f32x4 z = {0.f, 0.f, 0.f, 0.f};
    #pragma unroll
    for (int m = 0; m < 4; ++m)
        #pragma unroll
        for (int n = 0; n < 4; ++n) acc[m][n] = z;
    gemm_core_nt(A, CH, Wfg, CH, CH, lds, lds + 8192, acc);
    epilogue_store_bf16(lds, acc, fg_t + ((size_t)b * SEQ + i0) * 128, 128,
                        nullptr, bias_fg);
}

// ---------------------------------------------------------------------------
// proj_h: h_b[b][c][l] = sum_k Wh[c][k] * xt[b][l][k] + bh[c]
// ---------------------------------------------------------------------------
__global__ __launch_bounds__(256) void proj_h_kernel(
    const unsigned short* __restrict__ xt, const unsigned short* __restrict__ Whb,
    const float* __restrict__ bh, unsigned short* __restrict__ h_b)
{
    __shared__ unsigned short lds[16384];
    const int b = blockIdx.z, l0 = blockIdx.x * 128, c0 = blockIdx.y * 128;
    const unsigned short* A = Whb + (size_t)c0 * CH;
    const unsigned short* B = xt + ((size_t)b * SEQ + l0) * CH;
    f32x4 acc[4][4];
    const f32x4 z = {0.f, 0.f, 0.f, 0.f};
    #pragma unroll
    for (int m = 0; m < 4; ++m)
        #pragma unroll
        for (int n = 0; n < 4; ++n) acc[m][n] = z;
    gemm_core_nt(A, CH, B, CH, CH, lds, lds + 8192, acc);
    epilogue_store_bf16(lds, acc,
                        h_b + ((size_t)b * CH + c0) * SEQ + l0, SEQ,
                        bh + c0, nullptr);
}

// ---------------------------------------------------------------------------
// Flash-fused scores+softmax+PV+residual.
// Block: 64 Q-rows (i) x full C=512. 8 waves; wave w owns c in [64w, 64w+64).
// Per j-tile (64): cooperative S (2 i-half x 4 j-quarter wave split) -> LDS,
// per-wave 8-row online softmax (m,l,alpha in LDS), P bf16 -> LDS (XOR-swz),
// h-tile staged to LDS (XOR-swz), per-wave PV MFMA acc[4][4] (i x c).
// Epilogue: /l, LDS transpose, coalesced float4 out = att + x.
// grid 256 = (i-block 32) x (batch 8); b = blockIdx.x & 7 pins batch -> XCD.
// ---------------------------------------------------------------------------
__global__ __launch_bounds__(512) void flash_kernel(
    const unsigned short* __restrict__ fg_t,
    const unsigned short* __restrict__ h_b,
    const float* __restrict__ x,
    float* __restrict__ out)
{
    __shared__ __align__(16) char smem[92160];
    unsigned short* h_lds = (unsigned short*)smem;            // 65536 B [512][64]swz
    unsigned short* P_lds = (unsigned short*)(smem + 65536);  //  8192 B [64][64]swz
    float* S_lds = (float*)(smem + 73728);                    // 17408 B [64][68]
    float* m_lds = (float*)(smem + 91136);                    //   256 B
    float* l_lds = (float*)(smem + 91392);                    //   256 B
    float* a_lds = (float*)(smem + 91648);                    //   256 B
    float* trans = (float*)smem;                              // epilogue reuse 64KB

    const int tid  = threadIdx.x;
    const int w    = tid >> 6, lane = tid & 63;
    const int fr   = lane & 15, hi = lane >> 4;
    const int flat = blockIdx.x;
    const int b    = flat & 7;
    const int i0   = (flat >> 3) * 64;
    const int ihalf = w & 1, jq = w >> 1;

    if (tid < 64) { m_lds[tid] = -INFINITY; l_lds[tid] = 0.f; }

    // Q frags (f part, cols 0..63), resident for whole block
    bf16x8 qf[2][2];
    #pragma unroll
    for (int m = 0; m < 2; ++m)
        #pragma unroll
        for (int kk = 0; kk < 2; ++kk)
            qf[m][kk] = *(const bf16x8*)(fg_t +
                ((size_t)b * SEQ + i0 + ihalf * 32 + m * 16 + fr) * 128 +
                kk * 32 + hi * 8);

    // tile-0 prefetch: g frags (direct global->reg) + h tile (reg-staged)
    bf16x8 greg[2];
    uint4 hreg[8];
    #pragma unroll
    for (int kk = 0; kk < 2; ++kk)
        greg[kk] = *(const bf16x8*)(fg_t +
            ((size_t)b * SEQ + jq * 16 + fr) * 128 + 64 + kk * 32 + hi * 8);
    #pragma unroll
    for (int q = 0; q < 8; ++q) {
        const int id = tid + q * 512, c = id >> 3, ch = id & 7;
        hreg[q] = *(const uint4*)(h_b + ((size_t)b * CH + c) * SEQ + ch * 8);
    }

    f32x4 acc[4][4];
    const f32x4 z = {0.f, 0.f, 0.f, 0.f};
    #pragma unroll
    for (int m = 0; m < 4; ++m)
        #pragma unroll
        for (int n = 0; n < 4; ++n) acc[m][n] = z;
    __syncthreads();

    for (int jt = 0; jt < 32; ++jt) {
        // ---- phase B: stage h tile, compute S subtile, write S to LDS ----
        #pragma unroll
        for (int q = 0; q < 8; ++q) {
            const int id = tid + q * 512, c = id >> 3, ch = id & 7;
            *(uint4*)&h_lds[c * 64 + ((ch ^ (c & 7)) * 8)] = hreg[q];
        }
        f32x4 sacc[2] = {z, z};
        #pragma unroll
        for (int kk = 0; kk < 2; ++kk)
            #pragma unroll
            for (int m = 0; m < 2; ++m)
                sacc[m] = __builtin_amdgcn_mfma_f32_16x16x32_bf16(
                    qf[m][kk], greg[kk], sacc[m], 0, 0, 0);
        #pragma unroll
        for (int m = 0; m < 2; ++m)
            #pragma unroll
            for (int e = 0; e < 4; ++e)
                S_lds[(ihalf * 32 + m * 16 + hi * 4 + e) * 68 + jq * 16 + fr] =
                    sacc[m][e];
        __syncthreads();

        // ---- phase C: online softmax (wave w owns rows w*8..w*8+8) ----
        #pragma unroll
        for (int rr = 0; rr < 8; ++rr) {
            const int r = w * 8 + rr;
            const float sv = S_lds[r * 68 + lane];
            float tmax = sv;
            #pragma unroll
            for (int off = 32; off > 0; off >>= 1)
                tmax = fmaxf(tmax, __shfl_xor(tmax, off));
            const float mo = m_lds[r];
            const float mn = fmaxf(mo, tmax);
            const float p = __expf(sv - mn);
            float ts = p;
            #pragma unroll
            for (int off = 32; off > 0; off >>= 1)
                ts += __shfl_xor(ts, off);
            if (lane == 0) {
                const float al = __expf(mo - mn);
                l_lds[r] = l_lds[r] * al + ts;
                m_lds[r] = mn;
                a_lds[r] = al;
            }
            P_lds[r * 64 + (((lane >> 3) ^ (r & 7)) << 3) + (lane & 7)] = f2b(p);
        }
        if (jt + 1 < 32) {   // prefetch next tile (overlaps with softmax+PV)
            #pragma unroll
            for (int kk = 0; kk < 2; ++kk)
                greg[kk] = *(const bf16x8*)(fg_t +
                    ((size_t)b * SEQ + (jt + 1) * 64 + jq * 16 + fr) * 128 +
                    64 + kk * 32 + hi * 8);
            #pragma unroll
            for (int q = 0; q < 8; ++q) {
                const int id = tid + q * 512, c = id >> 3, ch = id & 7;
                hreg[q] = *(const uint4*)(h_b + ((size_t)b * CH + c) * SEQ +
                                          (jt + 1) * 64 + ch * 8);
            }
        }
        __syncthreads();

        // ---- phase D: rescale acc by alpha[row], PV MFMAs ----
        #pragma unroll
        for (int m = 0; m < 4; ++m)
            #pragma unroll
            for (int e = 0; e < 4; ++e) {
                const float al = a_lds[m * 16 + hi * 4 + e];
                #pragma unroll
                for (int n = 0; n < 4; ++n)
                    acc[m][n][e] *= al;
            }
        #pragma unroll
        for (int kk = 0; kk < 2; ++kk) {
            bf16x8 pa[4], hb[4];
            #pragma unroll
            for (int m = 0; m < 4; ++m)
                pa[m] = *(const bf16x8*)&P_lds[(m * 16 + fr) * 64 +
                                               (((kk * 4 + hi) ^ (fr & 7)) << 3)];
            #pragma unroll
            for (int n = 0; n < 4; ++n)
                hb[n] = *(const bf16x8*)&h_lds[(w * 64 + n * 16 + fr) * 64 +
                                               (((kk * 4 + hi) ^ (fr & 7)) << 3)];
            #pragma unroll
            for (int m = 0; m < 4; ++m)
                #pragma unroll
                for (int n = 0; n < 4; ++n)
                    acc[m][n] = __builtin_amdgcn_mfma_f32_16x16x32_bf16(
                        pa[m], hb[n], acc[m][n], 0, 0, 0);
        }
        __syncthreads();
    }

    // ---- epilogue: /l, transpose via LDS, coalesced out = att + x ----
    #pragma unroll
    for (int round = 0; round < 2; ++round) {
        __syncthreads();
        if ((w >> 2) == round) {
            float* T = trans + (w & 3) * 4096;   // [64 c][64 i] f32, chunk-swz
            #pragma unroll
            for (int m = 0; m < 4; ++m)
                #pragma unroll
                for (int e = 0; e < 4; ++e) {
                    const float inv = 1.f / l_lds[m * 16 + hi * 4 + e];
                    #pragma unroll
                    for (int n = 0; n < 4; ++n)
                        T[(n * 16 + fr) * 64 + (((m * 4 + hi) ^ fr) << 2) + e] =
                            acc[m][n][e] * inv;
                }
        }
        __syncthreads();
        #pragma unroll
        for (int q = 0; q < 8; ++q) {
            const int id = tid + q * 512;
            const int c_rel = id >> 4, ich = id & 15;
            const int slot = c_rel >> 6, c_in = c_rel & 63;
            f32x4 v = *(const f32x4*)(trans + slot * 4096 + c_in * 64 +
                                      ((ich ^ (c_in & 15)) << 2));
            const size_t ga = ((size_t)b * CH + round * 256 + c_rel) * SEQ +
                              i0 + ich * 4;
            f32x4 xv = *(const f32x4*)(x + ga);
            *(f32x4*)(out + ga) = v + xv;
        }
    }
}

// ---------------------------------------------------------------------------
extern "C" void kernel_launch(void* const* d_in, const int* in_sizes, int n_in,
                              void* d_out, int out_size, void* d_ws, size_t ws_size,
                              hipStream_t stream)
{
    const float* x   = (const float*)d_in[0];
    const float* Wf  = (const float*)d_in[1];
    const float* bf_ = (const float*)d_in[2];
    const float* Wg  = (const float*)d_in[3];
    const float* bg_ = (const float*)d_in[4];
    const float* Wh  = (const float*)d_in[5];
    const float* bh  = (const float*)d_in[6];
    float* out = (float*)d_out;

    unsigned short* ws = (unsigned short*)d_ws;
    size_t off = 0;
    unsigned short* xt   = ws + off; off += (size_t)BATCH * SEQ * CH;   // 8,388,608
    unsigned short* Wfgb = ws + off; off += 128 * CH;                   // 65,536
    unsigned short* Whb  = ws + off; off += CH * CH;                    // 262,144
    unsigned short* fg_t = ws + off; off += (size_t)BATCH * SEQ * 128;  // 2,097,152
    unsigned short* h_b  = ws + off; off += (size_t)BATCH * CH * SEQ;   // 8,388,608
    float* bias_fg = (float*)(ws + off);                                // 128 fp32

    transpose_cast_kernel<<<dim3(SEQ / 64, CH / 64, BATCH), 256, 0, stream>>>(x, xt);
    castw_kernel<<<dim3(1024), 256, 0, stream>>>(Wf, Wg, Wh, bf_, bg_, Wfgb, Whb, bias_fg);
    proj_fg_kernel<<<dim3(SEQ / 128, 1, BATCH), 256, 0, stream>>>(xt, Wfgb, bias_fg, fg_t);
    proj_h_kernel<<<dim3(SEQ / 128, CH / 128, BATCH), 256, 0, stream>>>(xt, Whb, bh, h_b);
    flash_kernel<<<dim3((SEQ / 64) * BATCH), 512, 0, stream>>>(fg_t, h_b, x, out);
}

// Round 5
// 395.546 us; speedup vs baseline: 1.1204x; 1.1204x over previous
//
#include <hip/hip_runtime.h>
#include <math.h>
#include <stdint.h>

#define BATCH 8
#define CH    512
#define SEQ   2048
#define CKDIM 64

typedef __attribute__((ext_vector_type(8))) short bf16x8;
typedef __attribute__((ext_vector_type(4))) float f32x4;

__device__ __forceinline__ unsigned short f2b(float f) {
    union { float f; uint32_t u; } v; v.f = f;
    uint32_t u = v.u;
    u += 0x7fffu + ((u >> 16) & 1u);   // round-to-nearest-even
    return (unsigned short)(u >> 16);
}

// ---------------------------------------------------------------------------
// x (B, C, L) fp32  ->  xt (B, L, C) bf16   (64x64 LDS-tiled transpose+cast)
// ---------------------------------------------------------------------------
__global__ __launch_bounds__(256) void transpose_cast_kernel(
    const float* __restrict__ x, unsigned short* __restrict__ xt)
{
    __shared__ float t[64][65];
    const int b = blockIdx.z, l0 = blockIdx.x * 64, c0 = blockIdx.y * 64;
    const int tx = threadIdx.x & 63, ty = threadIdx.x >> 6;
    #pragma unroll
    for (int q = 0; q < 16; ++q)
        t[ty + q * 4][tx] = x[((size_t)b * CH + c0 + ty + q * 4) * SEQ + l0 + tx];
    __syncthreads();
    #pragma unroll
    for (int q = 0; q < 16; ++q)
        xt[((size_t)b * SEQ + l0 + ty + q * 4) * CH + c0 + tx] = f2b(t[tx][ty + q * 4]);
}

// ---------------------------------------------------------------------------
// Weight cast: Wfg_b = concat(Wf, Wg) bf16 (128 x 512), Wh_b bf16 (512 x 512),
// bias_fg fp32[128] = concat(bf, bg).
// ---------------------------------------------------------------------------
__global__ __launch_bounds__(256) void castw_kernel(
    const float* __restrict__ Wf, const float* __restrict__ Wg,
    const float* __restrict__ Wh, const float* __restrict__ bf_,
    const float* __restrict__ bg_, unsigned short* __restrict__ Wfgb,
    unsigned short* __restrict__ Whb, float* __restrict__ bias_fg)
{
    const int i = blockIdx.x * 256 + threadIdx.x;
    if (i < 128) bias_fg[i] = (i < 64) ? bf_[i] : bg_[i - 64];
    if (i < 65536) Wfgb[i] = f2b((i < 32768) ? Wf[i] : Wg[i - 32768]);
    if (i < 262144) Whb[i] = f2b(Wh[i]);
}

// ---------------------------------------------------------------------------
// NT bf16 GEMM core (proven round 3: 0 LDS bank conflicts).
// ---------------------------------------------------------------------------
__device__ __attribute__((always_inline)) inline void gemm_core_nt(
    const unsigned short* __restrict__ A, const int ldA,
    const unsigned short* __restrict__ B, const int ldB,
    const int K,
    unsigned short* __restrict__ ldsA, unsigned short* __restrict__ ldsB,
    f32x4 acc[4][4])
{
    const int tid  = threadIdx.x;
    const int lane = tid & 63;
    const int wm   = tid >> 7;
    const int wn   = (tid >> 6) & 1;
    const int fr   = lane & 15;
    const int hi   = lane >> 4;
    const int xo   = lane & 7;

    int goA[4], goB[4], lo[4];
    #pragma unroll
    for (int it = 0; it < 4; ++it) {
        const int idx = tid + it * 256;
        const int row = idx >> 3;
        const int ch  = idx & 7;
        goA[it] = row * ldA + ch * 8;
        goB[it] = row * ldB + ch * 8;
        lo[it]  = row * 64 + ((ch ^ (row & 7)) * 8);
    }
    int aoff[4], boff[4];
    #pragma unroll
    for (int f = 0; f < 4; ++f) {
        aoff[f] = (wm * 64 + f * 16 + fr) * 64;
        boff[f] = (wn * 64 + f * 16 + fr) * 64;
    }
    const int coff0 = ((0 + hi) ^ xo) * 8;
    const int coff1 = ((4 + hi) ^ xo) * 8;

    uint4 ra[4], rb[4];
    #pragma unroll
    for (int it = 0; it < 4; ++it) {
        ra[it] = *(const uint4*)(A + goA[it]);
        rb[it] = *(const uint4*)(B + goB[it]);
    }

    for (int k0 = 0; k0 < K; k0 += 64) {
        #pragma unroll
        for (int it = 0; it < 4; ++it) {
            *(uint4*)&ldsA[lo[it]] = ra[it];
            *(uint4*)&ldsB[lo[it]] = rb[it];
        }
        __syncthreads();
        if (k0 + 64 < K) {
            #pragma unroll
            for (int it = 0; it < 4; ++it) {
                ra[it] = *(const uint4*)(A + goA[it] + k0 + 64);
                rb[it] = *(const uint4*)(B + goB[it] + k0 + 64);
            }
        }
        #pragma unroll
        for (int kk = 0; kk < 2; ++kk) {
            const int co = kk ? coff1 : coff0;
            bf16x8 af[4], bg[4];
            #pragma unroll
            for (int f = 0; f < 4; ++f) {
                af[f] = *(const bf16x8*)&ldsA[aoff[f] + co];
                bg[f] = *(const bf16x8*)&ldsB[boff[f] + co];
            }
            #pragma unroll
            for (int m = 0; m < 4; ++m)
                #pragma unroll
                for (int n = 0; n < 4; ++n)
                    acc[m][n] = __builtin_amdgcn_mfma_f32_16x16x32_bf16(
                        af[m], bg[n], acc[m][n], 0, 0, 0);
        }
        __syncthreads();
    }
}

__device__ __attribute__((always_inline)) inline void epilogue_store_bf16(
    unsigned short* __restrict__ lds, f32x4 acc[4][4],
    unsigned short* __restrict__ outBase, const int ldOut,
    const float* __restrict__ rowBias, const float* __restrict__ colBias)
{
    const int tid = threadIdx.x;
    const int lane = tid & 63;
    const int wm = tid >> 7, wn = (tid >> 6) & 1;
    const int fr = lane & 15, hi = lane >> 4;
    #pragma unroll
    for (int m = 0; m < 4; ++m) {
        const int m0 = wm * 64 + m * 16 + hi * 4;
        #pragma unroll
        for (int n = 0; n < 4; ++n) {
            const int nn = wn * 64 + n * 16 + fr;
            const float cb = colBias ? colBias[nn] : 0.f;
            #pragma unroll
            for (int e = 0; e < 4; ++e) {
                float v = acc[m][n][e] + cb;
                if (rowBias) v += rowBias[m0 + e];
                lds[(m0 + e) * 128 + nn] = f2b(v);
            }
        }
    }
    __syncthreads();
    #pragma unroll
    for (int q = 0; q < 8; ++q) {
        const int idx = tid + q * 256;
        const int row = idx >> 4, ch = idx & 15;
        *(uint4*)&outBase[(size_t)row * ldOut + ch * 8] =
            *(const uint4*)&lds[row * 128 + ch * 8];
    }
}

// ---------------------------------------------------------------------------
// proj_fg: fg_t[b][i][n] = sum_c xt[b][i][c] * Wfg[n][c] + bias_fg[n]
// ---------------------------------------------------------------------------
__global__ __launch_bounds__(256) void proj_fg_kernel(
    const unsigned short* __restrict__ xt, const unsigned short* __restrict__ Wfg,
    const float* __restrict__ bias_fg, unsigned short* __restrict__ fg_t)
{
    __shared__ unsigned short lds[16384];
    const int b = blockIdx.z, i0 = blockIdx.x * 128;
    const unsigned short* A = xt + ((size_t)b * SEQ + i0) * CH;
    f32x4 acc[4][4];
    const f32x4 z = {0.f, 0.f, 0.f, 0.f};
    #pragma unroll
    for (int m = 0; m < 4; ++m)
        #pragma unroll
        for (int n = 0; n < 4; ++n) acc[m][n] = z;
    gemm_core_nt(A, CH, Wfg, CH, CH, lds, lds + 8192, acc);
    epilogue_store_bf16(lds, acc, fg_t + ((size_t)b * SEQ + i0) * 128, 128,
                        nullptr, bias_fg);
}

// ---------------------------------------------------------------------------
// proj_h: h_b[b][c][l] = sum_k Wh[c][k] * xt[b][l][k] + bh[c]
// ---------------------------------------------------------------------------
__global__ __launch_bounds__(256) void proj_h_kernel(
    const unsigned short* __restrict__ xt, const unsigned short* __restrict__ Whb,
    const float* __restrict__ bh, unsigned short* __restrict__ h_b)
{
    __shared__ unsigned short lds[16384];
    const int b = blockIdx.z, l0 = blockIdx.x * 128, c0 = blockIdx.y * 128;
    const unsigned short* A = Whb + (size_t)c0 * CH;
    const unsigned short* B = xt + ((size_t)b * SEQ + l0) * CH;
    f32x4 acc[4][4];
    const f32x4 z = {0.f, 0.f, 0.f, 0.f};
    #pragma unroll
    for (int m = 0; m < 4; ++m)
        #pragma unroll
        for (int n = 0; n < 4; ++n) acc[m][n] = z;
    gemm_core_nt(A, CH, B, CH, CH, lds, lds + 8192, acc);
    epilogue_store_bf16(lds, acc,
                        h_b + ((size_t)b * CH + c0) * SEQ + l0, SEQ,
                        bh + c0, nullptr);
}

// ---------------------------------------------------------------------------
// Flash v2: swapped-QK^T, lane-local softmax, wave specialization.
// Block = 64 i-rows x 256 c (half of C); grid 512 = 8 batch x 2 chalf x 32 i.
// Waves 0-3: S = mfma(g, q) for i-quarter w -> lane (fr,hi) holds
//   S[j=16m+4hi+e][i=16w+fr]; in-reg softmax (15 max + 2 shfl_xor), m/l in
//   regs, alpha -> al_lds, P -> P_lds (b64 packed writes, XOR-swz layout).
// Waves 4-7: stage h tile regs->LDS + prefetch next tile (global->reg).
// PV (all 8 waves): c-slice 32/wave, XOR-swz b128 frag reads (proven 0-conf),
//   per-lane alpha rescale. 2 barriers/tile.
// Epilogue: /l, LDS transpose (2 rounds through 32KB), coalesced f32x4 out.
// ---------------------------------------------------------------------------
__global__ __launch_bounds__(512, 4) void flash_kernel(
    const unsigned short* __restrict__ fg_t,
    const unsigned short* __restrict__ h_b,
    const float* __restrict__ x,
    float* __restrict__ out)
{
    __shared__ __align__(16) char smem[41472];
    unsigned short* h_lds = (unsigned short*)smem;            // 32768 B [256][64]swz
    unsigned short* P_lds = (unsigned short*)(smem + 32768);  //  8192 B [64][64]swz
    float* al_lds = (float*)(smem + 40960);                   //   256 B
    float* il_lds = (float*)(smem + 41216);                   //   256 B
    float* trans  = (float*)smem;                             // epilogue reuse 32KB

    const int tid  = threadIdx.x;
    const int w    = tid >> 6, lane = tid & 63;
    const int fr   = lane & 15, hi = lane >> 4;
    const int flat = blockIdx.x;
    const int b     = flat & 7;
    const int chalf = (flat >> 3) & 1;
    const int i0    = (flat >> 4) * 64;
    const int c_base = chalf * 256;

    const f32x4 z = {0.f, 0.f, 0.f, 0.f};
    f32x4 acc[2][4];   // [mc][n]: out[c = w*32+16mc+4hi+e][i = 16n+fr]
    #pragma unroll
    for (int mc = 0; mc < 2; ++mc)
        #pragma unroll
        for (int n = 0; n < 4; ++n) acc[mc][n] = z;

    float m_run = -INFINITY, l_run = 0.f;
    bf16x8 qf[2];
    uint4 hreg[8];

    if (w < 4) {
        // q-frag (f cols 0..63), rows i = i0 + 16w + fr, persistent
        #pragma unroll
        for (int kk = 0; kk < 2; ++kk)
            qf[kk] = *(const bf16x8*)(fg_t +
                ((size_t)b * SEQ + i0 + 16 * w + fr) * 128 + kk * 32 + hi * 8);
    } else {
        const int lid = tid - 256;
        #pragma unroll
        for (int q = 0; q < 8; ++q) {
            const int id = lid + q * 256, c = id >> 3, ch = id & 7;
            hreg[q] = *(const uint4*)(h_b +
                ((size_t)b * CH + c_base + c) * SEQ + ch * 8);
        }
    }

    for (int jt = 0; jt < 32; ++jt) {
        __syncthreads();   // prev PV done: h_lds/P_lds writable
        if (w >= 4) {
            const int lid = tid - 256;
            #pragma unroll
            for (int q = 0; q < 8; ++q) {
                const int id = lid + q * 256, c = id >> 3, ch = id & 7;
                *(uint4*)&h_lds[c * 64 + ((ch ^ (c & 7)) * 8)] = hreg[q];
            }
            if (jt + 1 < 32) {
                #pragma unroll
                for (int q = 0; q < 8; ++q) {
                    const int id = lid + q * 256, c = id >> 3, ch = id & 7;
                    hreg[q] = *(const uint4*)(h_b +
                        ((size_t)b * CH + c_base + c) * SEQ + (jt + 1) * 64 + ch * 8);
                }
            }
        } else {
            // ---- S = mfma(g, q): lane holds S[j=16m+4hi+e][i=16w+fr] ----
            f32x4 sacc[4] = {z, z, z, z};
            #pragma unroll
            for (int kk = 0; kk < 2; ++kk)
                #pragma unroll
                for (int m = 0; m < 4; ++m) {
                    bf16x8 ga = *(const bf16x8*)(fg_t +
                        ((size_t)b * SEQ + jt * 64 + 16 * m + fr) * 128 +
                        64 + kk * 32 + hi * 8);
                    sacc[m] = __builtin_amdgcn_mfma_f32_16x16x32_bf16(
                        ga, qf[kk], sacc[m], 0, 0, 0);
                }
            // ---- lane-local online softmax ----
            float tmax = -INFINITY;
            #pragma unroll
            for (int m = 0; m < 4; ++m)
                #pragma unroll
                for (int e = 0; e < 4; ++e)
                    tmax = fmaxf(tmax, sacc[m][e]);
            tmax = fmaxf(tmax, __shfl_xor(tmax, 16));
            tmax = fmaxf(tmax, __shfl_xor(tmax, 32));
            const float mn = fmaxf(m_run, tmax);
            const float al = __expf(m_run - mn);
            float p[4][4];
            float ts = 0.f;
            #pragma unroll
            for (int m = 0; m < 4; ++m)
                #pragma unroll
                for (int e = 0; e < 4; ++e) {
                    p[m][e] = __expf(sacc[m][e] - mn);
                    ts += p[m][e];
                }
            ts += __shfl_xor(ts, 16);
            ts += __shfl_xor(ts, 32);
            l_run = l_run * al + ts;
            m_run = mn;
            if (hi == 0) al_lds[16 * w + fr] = al;
            // ---- P write: row i=16w+fr, 4 bf16 packed -> b64, XOR-swz ----
            #pragma unroll
            for (int m = 0; m < 4; ++m) {
                uint2 val;
                val.x = (uint32_t)f2b(p[m][0]) | ((uint32_t)f2b(p[m][1]) << 16);
                val.y = (uint32_t)f2b(p[m][2]) | ((uint32_t)f2b(p[m][3]) << 16);
                const int chunk = (2 * m + (hi >> 1)) ^ (fr & 7);
                *(uint2*)&P_lds[(16 * w + fr) * 64 + chunk * 8 + (hi & 1) * 4] = val;
            }
        }
        __syncthreads();   // h_lds + P_lds + al_lds ready

        // ---- PV: all waves, c-slice = [w*32, w*32+32) ----
        float alv[4];
        #pragma unroll
        for (int n = 0; n < 4; ++n) alv[n] = al_lds[16 * n + fr];
        #pragma unroll
        for (int mc = 0; mc < 2; ++mc)
            #pragma unroll
            for (int n = 0; n < 4; ++n)
                #pragma unroll
                for (int e = 0; e < 4; ++e)
                    acc[mc][n][e] *= alv[n];
        #pragma unroll
        for (int kk = 0; kk < 2; ++kk) {
            const int co = ((kk * 4 + hi) ^ (fr & 7)) * 8;
            bf16x8 ha[2], pb[4];
            #pragma unroll
            for (int mc = 0; mc < 2; ++mc)
                ha[mc] = *(const bf16x8*)&h_lds[(w * 32 + 16 * mc + fr) * 64 + co];
            #pragma unroll
            for (int n = 0; n < 4; ++n)
                pb[n] = *(const bf16x8*)&P_lds[(16 * n + fr) * 64 + co];
            #pragma unroll
            for (int mc = 0; mc < 2; ++mc)
                #pragma unroll
                for (int n = 0; n < 4; ++n)
                    acc[mc][n] = __builtin_amdgcn_mfma_f32_16x16x32_bf16(
                        ha[mc], pb[n], acc[mc][n], 0, 0, 0);
        }
    }

    // ---- epilogue ----
    __syncthreads();
    if (w < 4 && hi == 0) il_lds[16 * w + fr] = 1.f / l_run;
    __syncthreads();
    float ilv[4];
    #pragma unroll
    for (int n = 0; n < 4; ++n) ilv[n] = il_lds[16 * n + fr];

    #pragma unroll
    for (int r = 0; r < 2; ++r) {
        __syncthreads();
        if ((w >> 2) == r) {
            #pragma unroll
            for (int mc = 0; mc < 2; ++mc)
                #pragma unroll
                for (int n = 0; n < 4; ++n)
                    #pragma unroll
                    for (int e = 0; e < 4; ++e) {
                        const int c_rel = (w & 3) * 32 + 16 * mc + hi * 4 + e;
                        trans[c_rel * 64 + ((16 * n + fr) ^ (hi << 4))] =
                            acc[mc][n][e] * ilv[n];
                    }
        }
        __syncthreads();
        #pragma unroll
        for (int q = 0; q < 4; ++q) {
            const int id = tid + q * 512;
            const int c_r = id >> 4, ich = id & 15;
            f32x4 v = *(const f32x4*)&trans[c_r * 64 +
                                            ((ich * 4) ^ (((c_r >> 2) & 3) << 4))];
            const size_t ga = ((size_t)b * CH + c_base + r * 128 + c_r) * SEQ +
                              i0 + ich * 4;
            f32x4 xv = *(const f32x4*)&x[ga];
            *(f32x4*)&out[ga] = v + xv;
        }
    }
}

// ---------------------------------------------------------------------------
extern "C" void kernel_launch(void* const* d_in, const int* in_sizes, int n_in,
                              void* d_out, int out_size, void* d_ws, size_t ws_size,
                              hipStream_t stream)
{
    const float* x   = (const float*)d_in[0];
    const float* Wf  = (const float*)d_in[1];
    const float* bf_ = (const float*)d_in[2];
    const float* Wg  = (const float*)d_in[3];
    const float* bg_ = (const float*)d_in[4];
    const float* Wh  = (const float*)d_in[5];
    const float* bh  = (const float*)d_in[6];
    float* out = (float*)d_out;

    unsigned short* ws = (unsigned short*)d_ws;
    size_t off = 0;
    unsigned short* xt   = ws + off; off += (size_t)BATCH * SEQ * CH;   // 8,388,608
    unsigned short* Wfgb = ws + off; off += 128 * CH;                   // 65,536
    unsigned short* Whb  = ws + off; off += CH * CH;                    // 262,144
    unsigned short* fg_t = ws + off; off += (size_t)BATCH * SEQ * 128;  // 2,097,152
    unsigned short* h_b  = ws + off; off += (size_t)BATCH * CH * SEQ;   // 8,388,608
    float* bias_fg = (float*)(ws + off);                                // 128 fp32

    transpose_cast_kernel<<<dim3(SEQ / 64, CH / 64, BATCH), 256, 0, stream>>>(x, xt);
    castw_kernel<<<dim3(1024), 256, 0, stream>>>(Wf, Wg, Wh, bf_, bg_, Wfgb, Whb, bias_fg);
    proj_fg_kernel<<<dim3(SEQ / 128, 1, BATCH), 256, 0, stream>>>(xt, Wfgb, bias_fg, fg_t);
    proj_h_kernel<<<dim3(SEQ / 128, CH / 128, BATCH), 256, 0, stream>>>(xt, Whb, bh, h_b);
    flash_kernel<<<dim3(512), 512, 0, stream>>>(fg_t, h_b, x, out);
}

// Round 7
// 395.518 us; speedup vs baseline: 1.1205x; 1.0001x over previous
//
#include <hip/hip_runtime.h>
#include <math.h>
#include <stdint.h>

#define BATCH 8
#define CH    512
#define SEQ   2048
#define CKDIM 64

typedef __attribute__((ext_vector_type(8))) short bf16x8;
typedef __attribute__((ext_vector_type(4))) float f32x4;

__device__ __forceinline__ unsigned short f2b(float f) {
    union { float f; uint32_t u; } v; v.f = f;
    uint32_t u = v.u;
    u += 0x7fffu + ((u >> 16) & 1u);   // round-to-nearest-even
    return (unsigned short)(u >> 16);
}

// ---------------------------------------------------------------------------
// x (B, C, L) fp32  ->  xt (B, L, C) bf16   (64x64 LDS-tiled transpose+cast)
// ---------------------------------------------------------------------------
__global__ __launch_bounds__(256) void transpose_cast_kernel(
    const float* __restrict__ x, unsigned short* __restrict__ xt)
{
    __shared__ float t[64][65];
    const int b = blockIdx.z, l0 = blockIdx.x * 64, c0 = blockIdx.y * 64;
    const int tx = threadIdx.x & 63, ty = threadIdx.x >> 6;
    #pragma unroll
    for (int q = 0; q < 16; ++q)
        t[ty + q * 4][tx] = x[((size_t)b * CH + c0 + ty + q * 4) * SEQ + l0 + tx];
    __syncthreads();
    #pragma unroll
    for (int q = 0; q < 16; ++q)
        xt[((size_t)b * SEQ + l0 + ty + q * 4) * CH + c0 + tx] = f2b(t[tx][ty + q * 4]);
}

// ---------------------------------------------------------------------------
// Weight cast: Wfg_b = concat(Wf, Wg) bf16 (128 x 512), Wh_b bf16 (512 x 512),
// bias_fg fp32[128] = concat(bf, bg).
// ---------------------------------------------------------------------------
__global__ __launch_bounds__(256) void castw_kernel(
    const float* __restrict__ Wf, const float* __restrict__ Wg,
    const float* __restrict__ Wh, const float* __restrict__ bf_,
    const float* __restrict__ bg_, unsigned short* __restrict__ Wfgb,
    unsigned short* __restrict__ Whb, float* __restrict__ bias_fg)
{
    const int i = blockIdx.x * 256 + threadIdx.x;
    if (i < 128) bias_fg[i] = (i < 64) ? bf_[i] : bg_[i - 64];
    if (i < 65536) Wfgb[i] = f2b((i < 32768) ? Wf[i] : Wg[i - 32768]);
    if (i < 262144) Whb[i] = f2b(Wh[i]);
}

// ---------------------------------------------------------------------------
// NT bf16 GEMM core (proven round 3: 0 LDS bank conflicts).
// ---------------------------------------------------------------------------
__device__ __attribute__((always_inline)) inline void gemm_core_nt(
    const unsigned short* __restrict__ A, const int ldA,
    const unsigned short* __restrict__ B, const int ldB,
    const int K,
    unsigned short* __restrict__ ldsA, unsigned short* __restrict__ ldsB,
    f32x4 acc[4][4])
{
    const int tid  = threadIdx.x;
    const int lane = tid & 63;
    const int wm   = tid >> 7;
    const int wn   = (tid >> 6) & 1;
    const int fr   = lane & 15;
    const int hi   = lane >> 4;
    const int xo   = lane & 7;

    int goA[4], goB[4], lo[4];
    #pragma unroll
    for (int it = 0; it < 4; ++it) {
        const int idx = tid + it * 256;
        const int row = idx >> 3;
        const int ch  = idx & 7;
        goA[it] = row * ldA + ch * 8;
        goB[it] = row * ldB + ch * 8;
        lo[it]  = row * 64 + ((ch ^ (row & 7)) * 8);
    }
    int aoff[4], boff[4];
    #pragma unroll
    for (int f = 0; f < 4; ++f) {
        aoff[f] = (wm * 64 + f * 16 + fr) * 64;
        boff[f] = (wn * 64 + f * 16 + fr) * 64;
    }
    const int coff0 = ((0 + hi) ^ xo) * 8;
    const int coff1 = ((4 + hi) ^ xo) * 8;

    uint4 ra[4], rb[4];
    #pragma unroll
    for (int it = 0; it < 4; ++it) {
        ra[it] = *(const uint4*)(A + goA[it]);
        rb[it] = *(const uint4*)(B + goB[it]);
    }

    for (int k0 = 0; k0 < K; k0 += 64) {
        #pragma unroll
        for (int it = 0; it < 4; ++it) {
            *(uint4*)&ldsA[lo[it]] = ra[it];
            *(uint4*)&ldsB[lo[it]] = rb[it];
        }
        __syncthreads();
        if (k0 + 64 < K) {
            #pragma unroll
            for (int it = 0; it < 4; ++it) {
                ra[it] = *(const uint4*)(A + goA[it] + k0 + 64);
                rb[it] = *(const uint4*)(B + goB[it] + k0 + 64);
            }
        }
        #pragma unroll
        for (int kk = 0; kk < 2; ++kk) {
            const int co = kk ? coff1 : coff0;
            bf16x8 af[4], bg[4];
            #pragma unroll
            for (int f = 0; f < 4; ++f) {
                af[f] = *(const bf16x8*)&ldsA[aoff[f] + co];
                bg[f] = *(const bf16x8*)&ldsB[boff[f] + co];
            }
            #pragma unroll
            for (int m = 0; m < 4; ++m)
                #pragma unroll
                for (int n = 0; n < 4; ++n)
                    acc[m][n] = __builtin_amdgcn_mfma_f32_16x16x32_bf16(
                        af[m], bg[n], acc[m][n], 0, 0, 0);
        }
        __syncthreads();
    }
}

__device__ __attribute__((always_inline)) inline void epilogue_store_bf16(
    unsigned short* __restrict__ lds, f32x4 acc[4][4],
    unsigned short* __restrict__ outBase, const int ldOut,
    const float* __restrict__ rowBias, const float* __restrict__ colBias)
{
    const int tid = threadIdx.x;
    const int lane = tid & 63;
    const int wm = tid >> 7, wn = (tid >> 6) & 1;
    const int fr = lane & 15, hi = lane >> 4;
    #pragma unroll
    for (int m = 0; m < 4; ++m) {
        const int m0 = wm * 64 + m * 16 + hi * 4;
        #pragma unroll
        for (int n = 0; n < 4; ++n) {
            const int nn = wn * 64 + n * 16 + fr;
            const float cb = colBias ? colBias[nn] : 0.f;
            #pragma unroll
            for (int e = 0; e < 4; ++e) {
                float v = acc[m][n][e] + cb;
                if (rowBias) v += rowBias[m0 + e];
                lds[(m0 + e) * 128 + nn] = f2b(v);
            }
        }
    }
    __syncthreads();
    #pragma unroll
    for (int q = 0; q < 8; ++q) {
        const int idx = tid + q * 256;
        const int row = idx >> 4, ch = idx & 15;
        *(uint4*)&outBase[(size_t)row * ldOut + ch * 8] =
            *(const uint4*)&lds[row * 128 + ch * 8];
    }
}

// ---------------------------------------------------------------------------
// proj_fg: fg_t[b][i][n] = sum_c xt[b][i][c] * Wfg[n][c] + bias_fg[n]
// ---------------------------------------------------------------------------
__global__ __launch_bounds__(256) void proj_fg_kernel(
    const unsigned short* __restrict__ xt, const unsigned short* __restrict__ Wfg,
    const float* __restrict__ bias_fg, unsigned short* __restrict__ fg_t)
{
    __shared__ unsigned short lds[16384];
    const int b = blockIdx.z, i0 = blockIdx.x * 128;
    const unsigned short* A = xt + ((size_t)b * SEQ + i0) * CH;
    f32x4 acc[4][4];
    const f32x4 z = {0.f, 0.f, 0.f, 0.f};
    #pragma unroll
    for (int m = 0; m < 4; ++m)
        #pragma unroll
        for (int n = 0; n < 4; ++n) acc[m][n] = z;
    gemm_core_nt(A, CH, Wfg, CH, CH, lds, lds + 8192, acc);
    epilogue_store_bf16(lds, acc, fg_t + ((size_t)b * SEQ + i0) * 128, 128,
                        nullptr, bias_fg);
}

// ---------------------------------------------------------------------------
// proj_h: h_b[b][c][l] = sum_k Wh[c][k] * xt[b][l][k] + bh[c]
// ---------------------------------------------------------------------------
__global__ __launch_bounds__(256) void proj_h_kernel(
    const unsigned short* __restrict__ xt, const unsigned short* __restrict__ Whb,
    const float* __restrict__ bh, unsigned short* __restrict__ h_b)
{
    __shared__ unsigned short lds[16384];
    const int b = blockIdx.z, l0 = blockIdx.x * 128, c0 = blockIdx.y * 128;
    const unsigned short* A = Whb + (size_t)c0 * CH;
    const unsigned short* B = xt + ((size_t)b * SEQ + l0) * CH;
    f32x4 acc[4][4];
    const f32x4 z = {0.f, 0.f, 0.f, 0.f};
    #pragma unroll
    for (int m = 0; m < 4; ++m)
        #pragma unroll
        for (int n = 0; n < 4; ++n) acc[m][n] = z;
    gemm_core_nt(A, CH, B, CH, CH, lds, lds + 8192, acc);
    epilogue_store_bf16(lds, acc,
                        h_b + ((size_t)b * CH + c0) * SEQ + l0, SEQ,
                        bh + c0, nullptr);
}

// ---------------------------------------------------------------------------
// Flash v2.1: identical algorithm to v2; __launch_bounds__(512) only (no
// min-waves arg). Round-5's (512,4) made the compiler clamp to 64 VGPRs and
// spill ~35B/thread/iter to scratch (WRITE_SIZE 322MB vs 33.5MB ideal).
// Round-4 evidence: plain (512) -> 112 VGPRs, zero spill.
// ---------------------------------------------------------------------------
__global__ __launch_bounds__(512) void flash_kernel(
    const unsigned short* __restrict__ fg_t,
    const unsigned short* __restrict__ h_b,
    const float* __restrict__ x,
    float* __restrict__ out)
{
    __shared__ __align__(16) char smem[41472];
    unsigned short* h_lds = (unsigned short*)smem;            // 32768 B [256][64]swz
    unsigned short* P_lds = (unsigned short*)(smem + 32768);  //  8192 B [64][64]swz
    float* al_lds = (float*)(smem + 40960);                   //   256 B
    float* il_lds = (float*)(smem + 41216);                   //   256 B
    float* trans  = (float*)smem;                             // epilogue reuse 32KB

    const int tid  = threadIdx.x;
    const int w    = tid >> 6, lane = tid & 63;
    const int fr   = lane & 15, hi = lane >> 4;
    const int flat = blockIdx.x;
    const int b     = flat & 7;
    const int chalf = (flat >> 3) & 1;
    const int i0    = (flat >> 4) * 64;
    const int c_base = chalf * 256;

    const f32x4 z = {0.f, 0.f, 0.f, 0.f};
    f32x4 acc[2][4];   // [mc][n]: out[c = w*32+16mc+4hi+e][i = 16n+fr]
    #pragma unroll
    for (int mc = 0; mc < 2; ++mc)
        #pragma unroll
        for (int n = 0; n < 4; ++n) acc[mc][n] = z;

    float m_run = -INFINITY, l_run = 0.f;
    bf16x8 qf[2];
    uint4 hreg[8];

    if (w < 4) {
        // q-frag (f cols 0..63), rows i = i0 + 16w + fr, persistent
        #pragma unroll
        for (int kk = 0; kk < 2; ++kk)
            qf[kk] = *(const bf16x8*)(fg_t +
                ((size_t)b * SEQ + i0 + 16 * w + fr) * 128 + kk * 32 + hi * 8);
    } else {
        const int lid = tid - 256;
        #pragma unroll
        for (int q = 0; q < 8; ++q) {
            const int id = lid + q * 256, c = id >> 3, ch = id & 7;
            hreg[q] = *(const uint4*)(h_b +
                ((size_t)b * CH + c_base + c) * SEQ + ch * 8);
        }
    }

    for (int jt = 0; jt < 32; ++jt) {
        __syncthreads();   // prev PV done: h_lds/P_lds writable
        if (w >= 4) {
            const int lid = tid - 256;
            #pragma unroll
            for (int q = 0; q < 8; ++q) {
                const int id = lid + q * 256, c = id >> 3, ch = id & 7;
                *(uint4*)&h_lds[c * 64 + ((ch ^ (c & 7)) * 8)] = hreg[q];
            }
            if (jt + 1 < 32) {
                #pragma unroll
                for (int q = 0; q < 8; ++q) {
                    const int id = lid + q * 256, c = id >> 3, ch = id & 7;
                    hreg[q] = *(const uint4*)(h_b +
                        ((size_t)b * CH + c_base + c) * SEQ + (jt + 1) * 64 + ch * 8);
                }
            }
        } else {
            // ---- S = mfma(g, q): lane holds S[j=16m+4hi+e][i=16w+fr] ----
            f32x4 sacc[4] = {z, z, z, z};
            #pragma unroll
            for (int kk = 0; kk < 2; ++kk)
                #pragma unroll
                for (int m = 0; m < 4; ++m) {
                    bf16x8 ga = *(const bf16x8*)(fg_t +
                        ((size_t)b * SEQ + jt * 64 + 16 * m + fr) * 128 +
                        64 + kk * 32 + hi * 8);
                    sacc[m] = __builtin_amdgcn_mfma_f32_16x16x32_bf16(
                        ga, qf[kk], sacc[m], 0, 0, 0);
                }
            // ---- lane-local online softmax ----
            float tmax = -INFINITY;
            #pragma unroll
            for (int m = 0; m < 4; ++m)
                #pragma unroll
                for (int e = 0; e < 4; ++e)
                    tmax = fmaxf(tmax, sacc[m][e]);
            tmax = fmaxf(tmax, __shfl_xor(tmax, 16));
            tmax = fmaxf(tmax, __shfl_xor(tmax, 32));
            const float mn = fmaxf(m_run, tmax);
            const float al = __expf(m_run - mn);
            float p[4][4];
            float ts = 0.f;
            #pragma unroll
            for (int m = 0; m < 4; ++m)
                #pragma unroll
                for (int e = 0; e < 4; ++e) {
                    p[m][e] = __expf(sacc[m][e] - mn);
                    ts += p[m][e];
                }
            ts += __shfl_xor(ts, 16);
            ts += __shfl_xor(ts, 32);
            l_run = l_run * al + ts;
            m_run = mn;
            if (hi == 0) al_lds[16 * w + fr] = al;
            // ---- P write: row i=16w+fr, 4 bf16 packed -> b64, XOR-swz ----
            #pragma unroll
            for (int m = 0; m < 4; ++m) {
                uint2 val;
                val.x = (uint32_t)f2b(p[m][0]) | ((uint32_t)f2b(p[m][1]) << 16);
                val.y = (uint32_t)f2b(p[m][2]) | ((uint32_t)f2b(p[m][3]) << 16);
                const int chunk = (2 * m + (hi >> 1)) ^ (fr & 7);
                *(uint2*)&P_lds[(16 * w + fr) * 64 + chunk * 8 + (hi & 1) * 4] = val;
            }
        }
        __syncthreads();   // h_lds + P_lds + al_lds ready

        // ---- PV: all waves, c-slice = [w*32, w*32+32) ----
        float alv[4];
        #pragma unroll
        for (int n = 0; n < 4; ++n) alv[n] = al_lds[16 * n + fr];
        #pragma unroll
        for (int mc = 0; mc < 2; ++mc)
            #pragma unroll
            for (int n = 0; n < 4; ++n)
                #pragma unroll
                for (int e = 0; e < 4; ++e)
                    acc[mc][n][e] *= alv[n];
        #pragma unroll
        for (int kk = 0; kk < 2; ++kk) {
            const int co = ((kk * 4 + hi) ^ (fr & 7)) * 8;
            bf16x8 ha[2], pb[4];
            #pragma unroll
            for (int mc = 0; mc < 2; ++mc)
                ha[mc] = *(const bf16x8*)&h_lds[(w * 32 + 16 * mc + fr) * 64 + co];
            #pragma unroll
            for (int n = 0; n < 4; ++n)
                pb[n] = *(const bf16x8*)&P_lds[(16 * n + fr) * 64 + co];
            #pragma unroll
            for (int mc = 0; mc < 2; ++mc)
                #pragma unroll
                for (int n = 0; n < 4; ++n)
                    acc[mc][n] = __builtin_amdgcn_mfma_f32_16x16x32_bf16(
                        ha[mc], pb[n], acc[mc][n], 0, 0, 0);
        }
    }

    // ---- epilogue ----
    __syncthreads();
    if (w < 4 && hi == 0) il_lds[16 * w + fr] = 1.f / l_run;
    __syncthreads();
    float ilv[4];
    #pragma unroll
    for (int n = 0; n < 4; ++n) ilv[n] = il_lds[16 * n + fr];

    #pragma unroll
    for (int r = 0; r < 2; ++r) {
        __syncthreads();
        if ((w >> 2) == r) {
            #pragma unroll
            for (int mc = 0; mc < 2; ++mc)
                #pragma unroll
                for (int n = 0; n < 4; ++n)
                    #pragma unroll
                    for (int e = 0; e < 4; ++e) {
                        const int c_rel = (w & 3) * 32 + 16 * mc + hi * 4 + e;
                        trans[c_rel * 64 + ((16 * n + fr) ^ (hi << 4))] =
                            acc[mc][n][e] * ilv[n];
                    }
        }
        __syncthreads();
        #pragma unroll
        for (int q = 0; q < 4; ++q) {
            const int id = tid + q * 512;
            const int c_r = id >> 4, ich = id & 15;
            f32x4 v = *(const f32x4*)&trans[c_r * 64 +
                                            ((ich * 4) ^ (((c_r >> 2) & 3) << 4))];
            const size_t ga = ((size_t)b * CH + c_base + r * 128 + c_r) * SEQ +
                              i0 + ich * 4;
            f32x4 xv = *(const f32x4*)&x[ga];
            *(f32x4*)&out[ga] = v + xv;
        }
    }
}

// ---------------------------------------------------------------------------
extern "C" void kernel_launch(void* const* d_in, const int* in_sizes, int n_in,
                              void* d_out, int out_size, void* d_ws, size_t ws_size,
                              hipStream_t stream)
{
    const float* x   = (const float*)d_in[0];
    const float* Wf  = (const float*)d_in[1];
    const float* bf_ = (const float*)d_in[2];
    const float* Wg  = (const float*)d_in[3];
    const float* bg_ = (const float*)d_in[4];
    const float* Wh  = (const float*)d_in[5];
    const float* bh  = (const float*)d_in[6];
    float* out = (float*)d_out;

    unsigned short* ws = (unsigned short*)d_ws;
    size_t off = 0;
    unsigned short* xt   = ws + off; off += (size_t)BATCH * SEQ * CH;   // 8,388,608
    unsigned short* Wfgb = ws + off; off += 128 * CH;                   // 65,536
    unsigned short* Whb  = ws + off; off += CH * CH;                    // 262,144
    unsigned short* fg_t = ws + off; off += (size_t)BATCH * SEQ * 128;  // 2,097,152
    unsigned short* h_b  = ws + off; off += (size_t)BATCH * CH * SEQ;   // 8,388,608
    float* bias_fg = (float*)(ws + off);                                // 128 fp32

    transpose_cast_kernel<<<dim3(SEQ / 64, CH / 64, BATCH), 256, 0, stream>>>(x, xt);
    castw_kernel<<<dim3(1024), 256, 0, stream>>>(Wf, Wg, Wh, bf_, bg_, Wfgb, Whb, bias_fg);
    proj_fg_kernel<<<dim3(SEQ / 128, 1, BATCH), 256, 0, stream>>>(xt, Wfgb, bias_fg, fg_t);
    proj_h_kernel<<<dim3(SEQ / 128, CH / 128, BATCH), 256, 0, stream>>>(xt, Whb, bh, h_b);
    flash_kernel<<<dim3(512), 512, 0, stream>>>(fg_t, h_b, x, out);
}

// Round 8
// 395.061 us; speedup vs baseline: 1.1218x; 1.0012x over previous
//
#include <hip/hip_runtime.h>
#include <math.h>
#include <stdint.h>

#define BATCH 8
#define CH    512
#define SEQ   2048
#define CKDIM 64

typedef __attribute__((ext_vector_type(8))) short bf16x8;
typedef __attribute__((ext_vector_type(4))) float f32x4;

__device__ __forceinline__ unsigned short f2b(float f) {
    union { float f; uint32_t u; } v; v.f = f;
    uint32_t u = v.u;
    u += 0x7fffu + ((u >> 16) & 1u);   // round-to-nearest-even
    return (unsigned short)(u >> 16);
}

// ---------------------------------------------------------------------------
// x (B, C, L) fp32  ->  xt (B, L, C) bf16   (64x64 LDS-tiled transpose+cast)
// ---------------------------------------------------------------------------
__global__ __launch_bounds__(256) void transpose_cast_kernel(
    const float* __restrict__ x, unsigned short* __restrict__ xt)
{
    __shared__ float t[64][65];
    const int b = blockIdx.z, l0 = blockIdx.x * 64, c0 = blockIdx.y * 64;
    const int tx = threadIdx.x & 63, ty = threadIdx.x >> 6;
    #pragma unroll
    for (int q = 0; q < 16; ++q)
        t[ty + q * 4][tx] = x[((size_t)b * CH + c0 + ty + q * 4) * SEQ + l0 + tx];
    __syncthreads();
    #pragma unroll
    for (int q = 0; q < 16; ++q)
        xt[((size_t)b * SEQ + l0 + ty + q * 4) * CH + c0 + tx] = f2b(t[tx][ty + q * 4]);
}

// ---------------------------------------------------------------------------
// Weight cast: Wfg_b = concat(Wf, Wg) bf16 (128 x 512), Wh_b bf16 (512 x 512),
// bias_fg fp32[128] = concat(bf, bg).
// ---------------------------------------------------------------------------
__global__ __launch_bounds__(256) void castw_kernel(
    const float* __restrict__ Wf, const float* __restrict__ Wg,
    const float* __restrict__ Wh, const float* __restrict__ bf_,
    const float* __restrict__ bg_, unsigned short* __restrict__ Wfgb,
    unsigned short* __restrict__ Whb, float* __restrict__ bias_fg)
{
    const int i = blockIdx.x * 256 + threadIdx.x;
    if (i < 128) bias_fg[i] = (i < 64) ? bf_[i] : bg_[i - 64];
    if (i < 65536) Wfgb[i] = f2b((i < 32768) ? Wf[i] : Wg[i - 32768]);
    if (i < 262144) Whb[i] = f2b(Wh[i]);
}

// ---------------------------------------------------------------------------
// NT bf16 GEMM core (proven round 3: 0 LDS bank conflicts).
// ---------------------------------------------------------------------------
__device__ __attribute__((always_inline)) inline void gemm_core_nt(
    const unsigned short* __restrict__ A, const int ldA,
    const unsigned short* __restrict__ B, const int ldB,
    const int K,
    unsigned short* __restrict__ ldsA, unsigned short* __restrict__ ldsB,
    f32x4 acc[4][4])
{
    const int tid  = threadIdx.x;
    const int lane = tid & 63;
    const int wm   = tid >> 7;
    const int wn   = (tid >> 6) & 1;
    const int fr   = lane & 15;
    const int hi   = lane >> 4;
    const int xo   = lane & 7;

    int goA[4], goB[4], lo[4];
    #pragma unroll
    for (int it = 0; it < 4; ++it) {
        const int idx = tid + it * 256;
        const int row = idx >> 3;
        const int ch  = idx & 7;
        goA[it] = row * ldA + ch * 8;
        goB[it] = row * ldB + ch * 8;
        lo[it]  = row * 64 + ((ch ^ (row & 7)) * 8);
    }
    int aoff[4], boff[4];
    #pragma unroll
    for (int f = 0; f < 4; ++f) {
        aoff[f] = (wm * 64 + f * 16 + fr) * 64;
        boff[f] = (wn * 64 + f * 16 + fr) * 64;
    }
    const int coff0 = ((0 + hi) ^ xo) * 8;
    const int coff1 = ((4 + hi) ^ xo) * 8;

    uint4 ra[4], rb[4];
    #pragma unroll
    for (int it = 0; it < 4; ++it) {
        ra[it] = *(const uint4*)(A + goA[it]);
        rb[it] = *(const uint4*)(B + goB[it]);
    }

    for (int k0 = 0; k0 < K; k0 += 64) {
        #pragma unroll
        for (int it = 0; it < 4; ++it) {
            *(uint4*)&ldsA[lo[it]] = ra[it];
            *(uint4*)&ldsB[lo[it]] = rb[it];
        }
        __syncthreads();
        if (k0 + 64 < K) {
            #pragma unroll
            for (int it = 0; it < 4; ++it) {
                ra[it] = *(const uint4*)(A + goA[it] + k0 + 64);
                rb[it] = *(const uint4*)(B + goB[it] + k0 + 64);
            }
        }
        #pragma unroll
        for (int kk = 0; kk < 2; ++kk) {
            const int co = kk ? coff1 : coff0;
            bf16x8 af[4], bg[4];
            #pragma unroll
            for (int f = 0; f < 4; ++f) {
                af[f] = *(const bf16x8*)&ldsA[aoff[f] + co];
                bg[f] = *(const bf16x8*)&ldsB[boff[f] + co];
            }
            #pragma unroll
            for (int m = 0; m < 4; ++m)
                #pragma unroll
                for (int n = 0; n < 4; ++n)
                    acc[m][n] = __builtin_amdgcn_mfma_f32_16x16x32_bf16(
                        af[m], bg[n], acc[m][n], 0, 0, 0);
        }
        __syncthreads();
    }
}

__device__ __attribute__((always_inline)) inline void epilogue_store_bf16(
    unsigned short* __restrict__ lds, f32x4 acc[4][4],
    unsigned short* __restrict__ outBase, const int ldOut,
    const float* __restrict__ rowBias, const float* __restrict__ colBias)
{
    const int tid = threadIdx.x;
    const int lane = tid & 63;
    const int wm = tid >> 7, wn = (tid >> 6) & 1;
    const int fr = lane & 15, hi = lane >> 4;
    #pragma unroll
    for (int m = 0; m < 4; ++m) {
        const int m0 = wm * 64 + m * 16 + hi * 4;
        #pragma unroll
        for (int n = 0; n < 4; ++n) {
            const int nn = wn * 64 + n * 16 + fr;
            const float cb = colBias ? colBias[nn] : 0.f;
            #pragma unroll
            for (int e = 0; e < 4; ++e) {
                float v = acc[m][n][e] + cb;
                if (rowBias) v += rowBias[m0 + e];
                lds[(m0 + e) * 128 + nn] = f2b(v);
            }
        }
    }
    __syncthreads();
    #pragma unroll
    for (int q = 0; q < 8; ++q) {
        const int idx = tid + q * 256;
        const int row = idx >> 4, ch = idx & 15;
        *(uint4*)&outBase[(size_t)row * ldOut + ch * 8] =
            *(const uint4*)&lds[row * 128 + ch * 8];
    }
}

// ---------------------------------------------------------------------------
// proj_fg: fg_t[b][i][n] = sum_c xt[b][i][c] * Wfg[n][c] + bias_fg[n]
// ---------------------------------------------------------------------------
__global__ __launch_bounds__(256) void proj_fg_kernel(
    const unsigned short* __restrict__ xt, const unsigned short* __restrict__ Wfg,
    const float* __restrict__ bias_fg, unsigned short* __restrict__ fg_t)
{
    __shared__ unsigned short lds[16384];
    const int b = blockIdx.z, i0 = blockIdx.x * 128;
    const unsigned short* A = xt + ((size_t)b * SEQ + i0) * CH;
    f32x4 acc[4][4];
    const f32x4 z = {0.f, 0.f, 0.f, 0.f};
    #pragma unroll
    for (int m = 0; m < 4; ++m)
        #pragma unroll
        for (int n = 0; n < 4; ++n) acc[m][n] = z;
    gemm_core_nt(A, CH, Wfg, CH, CH, lds, lds + 8192, acc);
    epilogue_store_bf16(lds, acc, fg_t + ((size_t)b * SEQ + i0) * 128, 128,
                        nullptr, bias_fg);
}

// ---------------------------------------------------------------------------
// proj_h: h_b[b][c][l] = sum_k Wh[c][k] * xt[b][l][k] + bh[c]
// ---------------------------------------------------------------------------
__global__ __launch_bounds__(256) void proj_h_kernel(
    const unsigned short* __restrict__ xt, const unsigned short* __restrict__ Whb,
    const float* __restrict__ bh, unsigned short* __restrict__ h_b)
{
    __shared__ unsigned short lds[16384];
    const int b = blockIdx.z, l0 = blockIdx.x * 128, c0 = blockIdx.y * 128;
    const unsigned short* A = Whb + (size_t)c0 * CH;
    const unsigned short* B = xt + ((size_t)b * SEQ + l0) * CH;
    f32x4 acc[4][4];
    const f32x4 z = {0.f, 0.f, 0.f, 0.f};
    #pragma unroll
    for (int m = 0; m < 4; ++m)
        #pragma unroll
        for (int n = 0; n < 4; ++n) acc[m][n] = z;
    gemm_core_nt(A, CH, B, CH, CH, lds, lds + 8192, acc);
    epilogue_store_bf16(lds, acc,
                        h_b + ((size_t)b * CH + c0) * SEQ + l0, SEQ,
                        bh + c0, nullptr);
}

// ---------------------------------------------------------------------------
// Flash v2.2: identical algorithm to v2/v2.1. LDS PADDED 41472 -> 57344 B.
// Why: gfx950 VGPR-occupancy steps are {64:8, 128:4, 256:2 waves/EU} (m69).
// The backend derives its occupancy target from LDS-limited blocks/CU:
//   41.4KB -> 3 blocks/CU -> 6 waves/EU target -> only the 64-VGPR step
//   reaches >=6 -> VGPR clamped to 64 -> ~90B/thr/iter scratch spill
//   (WRITE_SIZE 316MB vs 33.5MB ideal; rounds 5 AND 7 both hit this;
//   round-5's explicit ",4" lost to the derived 6).
// 56KB -> 2 blocks/CU -> 4 waves/EU target -> 128-VGPR budget >= ~110 needed
// -> no spill. 3 blocks/CU was only ever reachable by spilling, so no loss.
// ---------------------------------------------------------------------------
__global__ __launch_bounds__(512) void flash_kernel(
    const unsigned short* __restrict__ fg_t,
    const unsigned short* __restrict__ h_b,
    const float* __restrict__ x,
    float* __restrict__ out)
{
    __shared__ __align__(16) char smem[57344];   // padded: see header comment
    unsigned short* h_lds = (unsigned short*)smem;            // 32768 B [256][64]swz
    unsigned short* P_lds = (unsigned short*)(smem + 32768);  //  8192 B [64][64]swz
    float* al_lds = (float*)(smem + 40960);                   //   256 B
    float* il_lds = (float*)(smem + 41216);                   //   256 B
    float* trans  = (float*)smem;                             // epilogue reuse 32KB

    const int tid  = threadIdx.x;
    const int w    = tid >> 6, lane = tid & 63;
    const int fr   = lane & 15, hi = lane >> 4;
    const int flat = blockIdx.x;
    const int b     = flat & 7;
    const int chalf = (flat >> 3) & 1;
    const int i0    = (flat >> 4) * 64;
    const int c_base = chalf * 256;

    const f32x4 z = {0.f, 0.f, 0.f, 0.f};
    f32x4 acc[2][4];   // [mc][n]: out[c = w*32+16mc+4hi+e][i = 16n+fr]
    #pragma unroll
    for (int mc = 0; mc < 2; ++mc)
        #pragma unroll
        for (int n = 0; n < 4; ++n) acc[mc][n] = z;

    float m_run = -INFINITY, l_run = 0.f;
    bf16x8 qf[2];
    uint4 hreg[8];

    if (w < 4) {
        // q-frag (f cols 0..63), rows i = i0 + 16w + fr, persistent
        #pragma unroll
        for (int kk = 0; kk < 2; ++kk)
            qf[kk] = *(const bf16x8*)(fg_t +
                ((size_t)b * SEQ + i0 + 16 * w + fr) * 128 + kk * 32 + hi * 8);
    } else {
        const int lid = tid - 256;
        #pragma unroll
        for (int q = 0; q < 8; ++q) {
            const int id = lid + q * 256, c = id >> 3, ch = id & 7;
            hreg[q] = *(const uint4*)(h_b +
                ((size_t)b * CH + c_base + c) * SEQ + ch * 8);
        }
    }

    for (int jt = 0; jt < 32; ++jt) {
        __syncthreads();   // prev PV done: h_lds/P_lds writable
        if (w >= 4) {
            const int lid = tid - 256;
            #pragma unroll
            for (int q = 0; q < 8; ++q) {
                const int id = lid + q * 256, c = id >> 3, ch = id & 7;
                *(uint4*)&h_lds[c * 64 + ((ch ^ (c & 7)) * 8)] = hreg[q];
            }
            if (jt + 1 < 32) {
                #pragma unroll
                for (int q = 0; q < 8; ++q) {
                    const int id = lid + q * 256, c = id >> 3, ch = id & 7;
                    hreg[q] = *(const uint4*)(h_b +
                        ((size_t)b * CH + c_base + c) * SEQ + (jt + 1) * 64 + ch * 8);
                }
            }
        } else {
            // ---- S = mfma(g, q): lane holds S[j=16m+4hi+e][i=16w+fr] ----
            f32x4 sacc[4] = {z, z, z, z};
            #pragma unroll
            for (int kk = 0; kk < 2; ++kk)
                #pragma unroll
                for (int m = 0; m < 4; ++m) {
                    bf16x8 ga = *(const bf16x8*)(fg_t +
                        ((size_t)b * SEQ + jt * 64 + 16 * m + fr) * 128 +
                        64 + kk * 32 + hi * 8);
                    sacc[m] = __builtin_amdgcn_mfma_f32_16x16x32_bf16(
                        ga, qf[kk], sacc[m], 0, 0, 0);
                }
            // ---- lane-local online softmax ----
            float tmax = -INFINITY;
            #pragma unroll
            for (int m = 0; m < 4; ++m)
                #pragma unroll
                for (int e = 0; e < 4; ++e)
                    tmax = fmaxf(tmax, sacc[m][e]);
            tmax = fmaxf(tmax, __shfl_xor(tmax, 16));
            tmax = fmaxf(tmax, __shfl_xor(tmax, 32));
            const float mn = fmaxf(m_run, tmax);
            const float al = __expf(m_run - mn);
            float p[4][4];
            float ts = 0.f;
            #pragma unroll
            for (int m = 0; m < 4; ++m)
                #pragma unroll
                for (int e = 0; e < 4; ++e) {
                    p[m][e] = __expf(sacc[m][e] - mn);
                    ts += p[m][e];
                }
            ts += __shfl_xor(ts, 16);
            ts += __shfl_xor(ts, 32);
            l_run = l_run * al + ts;
            m_run = mn;
            if (hi == 0) al_lds[16 * w + fr] = al;
            // ---- P write: row i=16w+fr, 4 bf16 packed -> b64, XOR-swz ----
            #pragma unroll
            for (int m = 0; m < 4; ++m) {
                uint2 val;
                val.x = (uint32_t)f2b(p[m][0]) | ((uint32_t)f2b(p[m][1]) << 16);
                val.y = (uint32_t)f2b(p[m][2]) | ((uint32_t)f2b(p[m][3]) << 16);
                const int chunk = (2 * m + (hi >> 1)) ^ (fr & 7);
                *(uint2*)&P_lds[(16 * w + fr) * 64 + chunk * 8 + (hi & 1) * 4] = val;
            }
        }
        __syncthreads();   // h_lds + P_lds + al_lds ready

        // ---- PV: all waves, c-slice = [w*32, w*32+32) ----
        float alv[4];
        #pragma unroll
        for (int n = 0; n < 4; ++n) alv[n] = al_lds[16 * n + fr];
        #pragma unroll
        for (int mc = 0; mc < 2; ++mc)
            #pragma unroll
            for (int n = 0; n < 4; ++n)
                #pragma unroll
                for (int e = 0; e < 4; ++e)
                    acc[mc][n][e] *= alv[n];
        #pragma unroll
        for (int kk = 0; kk < 2; ++kk) {
            const int co = ((kk * 4 + hi) ^ (fr & 7)) * 8;
            bf16x8 ha[2], pb[4];
            #pragma unroll
            for (int mc = 0; mc < 2; ++mc)
                ha[mc] = *(const bf16x8*)&h_lds[(w * 32 + 16 * mc + fr) * 64 + co];
            #pragma unroll
            for (int n = 0; n < 4; ++n)
                pb[n] = *(const bf16x8*)&P_lds[(16 * n + fr) * 64 + co];
            #pragma unroll
            for (int mc = 0; mc < 2; ++mc)
                #pragma unroll
                for (int n = 0; n < 4; ++n)
                    acc[mc][n] = __builtin_amdgcn_mfma_f32_16x16x32_bf16(
                        ha[mc], pb[n], acc[mc][n], 0, 0, 0);
        }
    }

    // ---- epilogue ----
    __syncthreads();
    if (w < 4 && hi == 0) il_lds[16 * w + fr] = 1.f / l_run;
    __syncthreads();
    float ilv[4];
    #pragma unroll
    for (int n = 0; n < 4; ++n) ilv[n] = il_lds[16 * n + fr];

    #pragma unroll
    for (int r = 0; r < 2; ++r) {
        __syncthreads();
        if ((w >> 2) == r) {
            #pragma unroll
            for (int mc = 0; mc < 2; ++mc)
                #pragma unroll
                for (int n = 0; n < 4; ++n)
                    #pragma unroll
                    for (int e = 0; e < 4; ++e) {
                        const int c_rel = (w & 3) * 32 + 16 * mc + hi * 4 + e;
                        trans[c_rel * 64 + ((16 * n + fr) ^ (hi << 4))] =
                            acc[mc][n][e] * ilv[n];
                    }
        }
        __syncthreads();
        #pragma unroll
        for (int q = 0; q < 4; ++q) {
            const int id = tid + q * 512;
            const int c_r = id >> 4, ich = id & 15;
            f32x4 v = *(const f32x4*)&trans[c_r * 64 +
                                            ((ich * 4) ^ (((c_r >> 2) & 3) << 4))];
            const size_t ga = ((size_t)b * CH + c_base + r * 128 + c_r) * SEQ +
                              i0 + ich * 4;
            f32x4 xv = *(const f32x4*)&x[ga];
            *(f32x4*)&out[ga] = v + xv;
        }
    }
}

// ---------------------------------------------------------------------------
extern "C" void kernel_launch(void* const* d_in, const int* in_sizes, int n_in,
                              void* d_out, int out_size, void* d_ws, size_t ws_size,
                              hipStream_t stream)
{
    const float* x   = (const float*)d_in[0];
    const float* Wf  = (const float*)d_in[1];
    const float* bf_ = (const float*)d_in[2];
    const float* Wg  = (const float*)d_in[3];
    const float* bg_ = (const float*)d_in[4];
    const float* Wh  = (const float*)d_in[5];
    const float* bh  = (const float*)d_in[6];
    float* out = (float*)d_out;

    unsigned short* ws = (unsigned short*)d_ws;
    size_t off = 0;
    unsigned short* xt   = ws + off; off += (size_t)BATCH * SEQ * CH;   // 8,388,608
    unsigned short* Wfgb = ws + off; off += 128 * CH;                   // 65,536
    unsigned short* Whb  = ws + off; off += CH * CH;                    // 262,144
    unsigned short* fg_t = ws + off; off += (size_t)BATCH * SEQ * 128;  // 2,097,152
    unsigned short* h_b  = ws + off; off += (size_t)BATCH * CH * SEQ;   // 8,388,608
    float* bias_fg = (float*)(ws + off);                                // 128 fp32

    transpose_cast_kernel<<<dim3(SEQ / 64, CH / 64, BATCH), 256, 0, stream>>>(x, xt);
    castw_kernel<<<dim3(1024), 256, 0, stream>>>(Wf, Wg, Wh, bf_, bg_, Wfgb, Whb, bias_fg);
    proj_fg_kernel<<<dim3(SEQ / 128, 1, BATCH), 256, 0, stream>>>(xt, Wfgb, bias_fg, fg_t);
    proj_h_kernel<<<dim3(SEQ / 128, CH / 128, BATCH), 256, 0, stream>>>(xt, Whb, bh, h_b);
    flash_kernel<<<dim3(512), 512, 0, stream>>>(fg_t, h_b, x, out);
}